// Round 2
// baseline (5675.748 us; speedup 1.0000x reference)
//
#include <hip/hip_runtime.h>
#include <cstdint>
#include <cstddef>

#define NN   4096      // neurons
#define NE   131072    // edges
#define NBAT 8         // batch
#define NT   128       // timesteps
#define NV   8192      // vocab
#define NK   4096      // = NN (GEMM K)
#define NM   1024      // = NBAT*NT (GEMM M)
#define DECAYF 0.99f
#define COOP_BLOCKS 256
#define COOP_THREADS 1024   // 8 batch x 8 strips x 16 nodes
#define NBARRIERS (NT * 5)  // 5 grid barriers per timestep

typedef short bf16x8 __attribute__((ext_vector_type(8)));
typedef float f32x4 __attribute__((ext_vector_type(4)));
typedef unsigned short u16x8 __attribute__((ext_vector_type(8)));

__device__ __forceinline__ unsigned short f2bf(float f) {
  unsigned int u = __builtin_bit_cast(unsigned int, f);
  u = u + 0x7fffu + ((u >> 16) & 1u);   // round-to-nearest-even
  return (unsigned short)(u >> 16);
}

// Coherent (cross-XCD) access: sc0 sc1, bypasses L1/L2, served at the
// memory-side coherence point. No fences needed anywhere.
__device__ __forceinline__ float cload(const float* p) {
  return __hip_atomic_load(p, __ATOMIC_RELAXED, __HIP_MEMORY_SCOPE_AGENT);
}
__device__ __forceinline__ float2 cload2(const float* p) {
  unsigned long long v = __hip_atomic_load((const unsigned long long*)p,
                                           __ATOMIC_RELAXED, __HIP_MEMORY_SCOPE_AGENT);
  return __builtin_bit_cast(float2, v);
}
__device__ __forceinline__ void cstore(float* p, float v) {
  __hip_atomic_store(p, v, __ATOMIC_RELAXED, __HIP_MEMORY_SCOPE_AGENT);
}
__device__ __forceinline__ int cloadi(const int* p) {
  return __hip_atomic_load(p, __ATOMIC_RELAXED, __HIP_MEMORY_SCOPE_AGENT);
}
__device__ __forceinline__ void cstorei(int* p, int v) {
  __hip_atomic_store(p, v, __ATOMIC_RELAXED, __HIP_MEMORY_SCOPE_AGENT);
}

// ---------------- prologue: CSR build ----------------
__global__ void k_hist(const int* __restrict__ dst, int* __restrict__ cnt) {
  int e = blockIdx.x * 256 + threadIdx.x;
  if (e < NE) atomicAdd(&cnt[dst[e]], 1);
}

__global__ void k_scan(const int* __restrict__ cnt, int* __restrict__ row_ptr,
                       int* __restrict__ cursor) {
  __shared__ int lds[256];
  int tid = threadIdx.x;
  int base = tid * 16;
  int loc[16];
  int s = 0;
  #pragma unroll
  for (int i = 0; i < 16; ++i) { loc[i] = s; s += cnt[base + i]; }
  lds[tid] = s;
  __syncthreads();
  for (int off = 1; off < 256; off <<= 1) {
    int v = lds[tid];
    int a = (tid >= off) ? lds[tid - off] : 0;
    __syncthreads();
    lds[tid] = v + a;
    __syncthreads();
  }
  int myoff = (tid == 0) ? 0 : lds[tid - 1];
  #pragma unroll
  for (int i = 0; i < 16; ++i) {
    int rp = myoff + loc[i];
    row_ptr[base + i] = rp;
    cursor[base + i] = rp;
  }
  if (tid == 255) row_ptr[NN] = lds[255];
}

__global__ void k_build(const int* __restrict__ src, const int* __restrict__ dst,
                        const float* __restrict__ Gx, const float* __restrict__ Gy,
                        const float* __restrict__ Gs, int* __restrict__ cursor,
                        int* __restrict__ src_s, int* __restrict__ orig_s,
                        float* __restrict__ Gx_s, float* __restrict__ Gy_s,
                        float* __restrict__ Gs_s) {
  int e = blockIdx.x * 256 + threadIdx.x;
  if (e >= NE) return;
  if (e == 0) {   // zero pad slot at index NE: inactive register slots point here
    src_s[NE] = 0;
    Gx_s[NE] = 0.f; Gy_s[NE] = 0.f; Gs_s[NE] = 0.f;
  }
  int d = dst[e];
  int pos = atomicAdd(&cursor[d], 1);
  src_s[pos] = src[e];
  orig_s[pos] = e;
  Gx_s[pos] = Gx[e];
  Gy_s[pos] = Gy[e];
  Gs_s[pos] = Gs[e];
}

// Gather all embeddings into (T, N, B) layout; also init y-half of xybuf = X[:,0,:]
__global__ void k_gatherX(const int* __restrict__ idx, const float* __restrict__ Wemb,
                          float* __restrict__ Xbuf, float* __restrict__ xybuf) {
  __shared__ float tile[256 * 9];   // +1 pad stride to kill bank conflicts
  int t = blockIdx.x >> 4;
  int nc = (blockIdx.x & 15) << 8;
  int tid = threadIdx.x;
  #pragma unroll
  for (int bb = 0; bb < 8; ++bb) {
    int row = idx[bb * NT + t];     // idx is (B,T)
    tile[tid * 9 + bb] = Wemb[(size_t)row * NN + nc + tid];
  }
  __syncthreads();
  float* dp = Xbuf + (size_t)t * (NN * NBAT) + (size_t)nc * NBAT;
  #pragma unroll
  for (int kk = 0; kk < 8; ++kk) dp[tid * 8 + kk] = tile[tid * 9 + kk];
  if (t == 0) {
    float* yp = xybuf + (size_t)nc * NBAT * 2;
    #pragma unroll
    for (int kk = 0; kk < 8; ++kk) yp[((tid * 8 + kk) << 1) + 1] = tile[tid * 9 + kk];
  }
}

__global__ void k_convW(const float* __restrict__ W, unsigned short* __restrict__ Wbf) {
  size_t base = ((size_t)blockIdx.x * 256 + threadIdx.x) * 8;
  float4 a = *(const float4*)(W + base);
  float4 b = *(const float4*)(W + base + 4);
  u16x8 hv;
  hv[0] = f2bf(a.x); hv[1] = f2bf(a.y); hv[2] = f2bf(a.z); hv[3] = f2bf(a.w);
  hv[4] = f2bf(b.x); hv[5] = f2bf(b.y); hv[6] = f2bf(b.z); hv[7] = f2bf(b.w);
  *(u16x8*)(Wbf + base) = hv;
}

// ---------------- grid barrier ----------------
// bar[0..255]    : per-block monotone arrive generation (worker leader stores)
// rel[i*16]      : per-block REPLICATED release line (64B apart) -> each worker
//                  spins on its OWN line: no reader contention, no master
//                  release-line hot spot. Master posts 256 lines with 4
//                  wave-wide store instructions.
__device__ __forceinline__ void gridbar(int* bar, int* rel, int& gen) {
  __syncthreads();   // vmcnt(0): all this block's coherent stores are at L3
  if (threadIdx.x == 0) {
    cstorei(&bar[blockIdx.x], gen + 1);
    while (cloadi(&rel[blockIdx.x << 4]) <= gen) __builtin_amdgcn_s_sleep(1);
  }
  ++gen;
  __syncthreads();
}

// ---------------- persistent recurrence kernel ----------------
// Worker blocks 0..255; block 256 = barrier master (wave 0 only).
// Worker mapping: g = b | h<<3 | n<<6 (b=batch lane, h=edge-strip, n=node).
// One wave = one node. Edge metadata for the first 64 edges of each node is
// register-resident (gather addresses + sigma); >64-edge nodes (not expected
// at mean degree 32, but handled for safety) fall back to memory.
// NOTE: __launch_bounds__(1024, 8) caps VGPR at 64 -> 2 blocks/CU capacity,
// guaranteeing all 257 blocks are co-resident (deadlock-free barrier).
__global__ __launch_bounds__(COOP_THREADS, 8) void k_loop(
    const int* __restrict__ row_ptr, const int* __restrict__ src_s,
    const float* __restrict__ Gx_s, const float* __restrict__ Gy_s,
    const float* __restrict__ Gs_s, float* __restrict__ sigma_s,
    const float* __restrict__ Xbuf, float* __restrict__ xybuf,
    float* __restrict__ Abuf, unsigned short* __restrict__ Abf,
    int* bar, int* rel,
    const int* __restrict__ orig_s, float* __restrict__ sig_out) {
  if (blockIdx.x == COOP_BLOCKS) {
    // ---- barrier master: wave 0 sweeps 256 arrive flags (strided so each
    // load instr is contiguous: 4x 256B = 16 line-requests/sweep), then posts
    // the release generation to 256 replicated lines (4 store instrs). ----
    if (threadIdx.x < 64) {
      const int lane = threadIdx.x;
      for (int g = 1; g <= NBARRIERS; ++g) {
        for (;;) {
          int v0 = cloadi(&bar[lane]);
          int v1 = cloadi(&bar[lane + 64]);
          int v2 = cloadi(&bar[lane + 128]);
          int v3 = cloadi(&bar[lane + 192]);
          int m = min(min(v0, v1), min(v2, v3));
          #pragma unroll
          for (int d = 1; d < 64; d <<= 1) m = min(m, __shfl_xor(m, d));
          if (m >= g) break;
        }
        #pragma unroll
        for (int k = 0; k < 4; ++k) cstorei(&rel[(lane + k * 64) << 4], g);
      }
    }
    return;
  }

  const int tid = threadIdx.x;
  const int g = blockIdx.x * COOP_THREADS + tid;
  const int b = g & 7;
  const int h = (g >> 3) & 7;
  const int n = g >> 6;
  const int rs = row_ptr[n];
  const int re = row_ptr[n + 1];
  const int rh = rs + h;
  const int nb8 = (n << 3) | b;
  const int nb16 = nb8 << 1;
  int gen = 0;

  // register-resident per-slot state: gather offset + sigma (slot s covers
  // edge jc = rs + h + (s>>2)*32 + (s&3)*8 ; inactive slots -> pad index NE,
  // whose G-values are 0 so every contribution masks to zero).
  int   r_sb[8];
  float r_sg[8];
  #pragma unroll
  for (int s = 0; s < 8; ++s) {
    int jc = rh + ((s >> 2) << 5) + ((s & 3) << 3);
    int j = (jc < re) ? jc : NE;
    r_sb[s] = (src_s[j] << 3) | b;
    r_sg[s] = 0.f;
  }
  const bool tail = (re - rs) > 64;   // memory fallback (degree > 64): rare/none

  for (int t = 0; t < NT; ++t) {
    const float* xp = Xbuf + (size_t)t * (NN * NBAT);
    #pragma unroll
    for (int layer = 0; layer < 2; ++layer) {
      // ---- S12: A[b,n] = sum x[b,src]*sigma ; hebbian ; sigma update ----
      {
        float xn = (layer == 0) ? xp[nb8] : cload(&xybuf[nb16]);
        float xv[8], yv[8];
        #pragma unroll
        for (int s = 0; s < 8; ++s) {
          if (layer == 0) {
            xv[s] = xp[r_sb[s]];                       // cached (read-only slab)
            yv[s] = cload(&xybuf[(r_sb[s] << 1) + 1]);
          } else {
            float2 p2 = cload2(&xybuf[r_sb[s] << 1]);  // one request: x AND y
            xv[s] = p2.x; yv[s] = p2.y;
          }
        }
        float acc = 0.f;
        #pragma unroll
        for (int s = 0; s < 8; ++s) {
          acc = fmaf(xv[s], r_sg[s], acc);             // OLD sigma (matches ref)
          float pv = yv[s] * xn;                       // y_t[b,src]*x_t[b,dst]
          pv += __shfl_xor(pv, 1);
          pv += __shfl_xor(pv, 2);
          pv += __shfl_xor(pv, 4);                     // sum over 8 batch lanes
          int jc = rh + ((s >> 2) << 5) + ((s & 3) << 3);
          int j = (jc < re) ? jc : NE;                 // Gs_s[NE]==0 masks pad
          r_sg[s] = (r_sg[s] + pv * 0.125f * Gs_s[j]) * DECAYF;
        }
        if (tail) {
          for (int j = rs + 64 + h; j < re; j += 8) {
            int sb2 = ((src_s[j] << 3) | b) << 1;
            float xvr = (layer == 0) ? xp[sb2 >> 1] : cload(&xybuf[sb2]);
            float yvr = cload(&xybuf[sb2 + 1]);
            float sgr = sigma_s[j];
            acc = fmaf(xvr, sgr, acc);
            float pvr = yvr * xn;
            pvr += __shfl_xor(pvr, 1);
            pvr += __shfl_xor(pvr, 2);
            pvr += __shfl_xor(pvr, 4);
            if (b == 0) sigma_s[j] = (sgr + pvr * 0.125f * Gs_s[j]) * DECAYF;
          }
        }
        acc += __shfl_xor(acc, 8);
        acc += __shfl_xor(acc, 16);
        acc += __shfl_xor(acc, 32);                    // combine 8 edge-strips
        if (h == 0) cstore(&Abuf[nb8], acc);
      }
      gridbar(bar, rel, gen);
      // ---- S3: y[b,n] = sum relu(A[b,src])*Gy ----
      {
        float av[8];
        #pragma unroll
        for (int s = 0; s < 8; ++s) av[s] = cload(&Abuf[r_sb[s]]);
        float acc = 0.f;
        #pragma unroll
        for (int s = 0; s < 8; ++s) {
          int jc = rh + ((s >> 2) << 5) + ((s & 3) << 3);
          int j = (jc < re) ? jc : NE;
          acc = fmaf(fmaxf(av[s], 0.f), Gy_s[j], acc);
        }
        if (tail)
          for (int j = rs + 64 + h; j < re; j += 8)
            acc = fmaf(fmaxf(cload(&Abuf[(src_s[j] << 3) | b]), 0.f), Gy_s[j], acc);
        acc += __shfl_xor(acc, 8);
        acc += __shfl_xor(acc, 16);
        acc += __shfl_xor(acc, 32);
        if (h == 0) cstore(&xybuf[nb16 + 1], acc);
      }
      gridbar(bar, rel, gen);
      // ---- S4: x[b,n] = relu(sum y[b,src]*Gx) ----
      {
        float yv2[8];
        #pragma unroll
        for (int s = 0; s < 8; ++s) yv2[s] = cload(&xybuf[(r_sb[s] << 1) + 1]);
        float acc = 0.f;
        #pragma unroll
        for (int s = 0; s < 8; ++s) {
          int jc = rh + ((s >> 2) << 5) + ((s & 3) << 3);
          int j = (jc < re) ? jc : NE;
          acc = fmaf(yv2[s], Gx_s[j], acc);
        }
        if (tail)
          for (int j = rs + 64 + h; j < re; j += 8)
            acc = fmaf(cload(&xybuf[(((src_s[j] << 3) | b) << 1) + 1]), Gx_s[j], acc);
        acc += __shfl_xor(acc, 8);
        acc += __shfl_xor(acc, 16);
        acc += __shfl_xor(acc, 32);
        if (layer == 0) {
          if (h == 0) cstore(&xybuf[nb16], fmaxf(acc, 0.f));
          gridbar(bar, rel, gen);
        } else if (h == 0) {
          // xs output straight into GEMM A-matrix (bf16), row m = b*T+t
          Abf[(size_t)((b << 7) | t) * NK + n] = f2bf(fmaxf(acc, 0.f));
        }
      }
      // no barrier after layer-2 S4: next step's x comes from Xbuf, and y/sigma
      // are produced before the next barrier; Abf is consumed post-kernel.
    }
  }
  // epilogue: sigma (registers + rare memory tail) back to original edge order
  if (b == 0) {
    #pragma unroll
    for (int s = 0; s < 8; ++s) {
      int jc = rh + ((s >> 2) << 5) + ((s & 3) << 3);
      if (jc < re) sig_out[orig_s[jc]] = r_sg[s];
    }
    if (tail)
      for (int j = rs + 64 + h; j < re; j += 8) sig_out[orig_s[j]] = sigma_s[j];
  }
}

// ---------------- bf16 MFMA GEMM: C[m,v] = sum_k A[m,k]*Bw[v,k] + bias[v] ----------------
__global__ __launch_bounds__(256) void k_gemm(const unsigned short* __restrict__ A,
                                              const unsigned short* __restrict__ Bw,
                                              const float* __restrict__ bias,
                                              float* __restrict__ C) {
  __shared__ __align__(16) unsigned short As[128 * 32];
  __shared__ __align__(16) unsigned short Bs[128 * 32];
  const int m0 = blockIdx.y * 128;
  const int v0 = blockIdx.x * 128;
  const int wave = threadIdx.x >> 6;
  const int lane = threadIdx.x & 63;
  const int wm = wave >> 1;
  const int wv = wave & 1;
  f32x4 acc[4][4] = {};

  const int srow = lane >> 2;
  const int skc = (lane & 3) * 8;

  for (int k0 = 0; k0 < NK; k0 += 32) {
    #pragma unroll
    for (int c = 0; c < 2; ++c) {
      int chunk = wave * 2 + c;
      int row = chunk * 16 + srow;
      __builtin_amdgcn_global_load_lds(
          (const __attribute__((address_space(1))) void*)(A + (size_t)(m0 + row) * NK + k0 + skc),
          (__attribute__((address_space(3))) void*)(As + chunk * 512), 16, 0, 0);
      __builtin_amdgcn_global_load_lds(
          (const __attribute__((address_space(1))) void*)(Bw + (size_t)(v0 + row) * NK + k0 + skc),
          (__attribute__((address_space(3))) void*)(Bs + chunk * 512), 16, 0, 0);
    }
    __syncthreads();
    bf16x8 af[4], bq[4];
    #pragma unroll
    for (int mi = 0; mi < 4; ++mi)
      af[mi] = *(const bf16x8*)(As + ((wm * 64 + mi * 16 + (lane & 15)) * 32 + (lane >> 4) * 8));
    #pragma unroll
    for (int ni = 0; ni < 4; ++ni)
      bq[ni] = *(const bf16x8*)(Bs + ((wv * 64 + ni * 16 + (lane & 15)) * 32 + (lane >> 4) * 8));
    #pragma unroll
    for (int mi = 0; mi < 4; ++mi)
      #pragma unroll
      for (int ni = 0; ni < 4; ++ni)
        acc[mi][ni] = __builtin_amdgcn_mfma_f32_16x16x32_bf16(af[mi], bq[ni], acc[mi][ni], 0, 0, 0);
    __syncthreads();
  }

  #pragma unroll
  for (int mi = 0; mi < 4; ++mi) {
    int mrow = m0 + wm * 64 + mi * 16 + ((lane >> 4) << 2);
    #pragma unroll
    for (int ni = 0; ni < 4; ++ni) {
      int vcol = v0 + wv * 64 + ni * 16 + (lane & 15);
      float bs = bias[vcol];
      f32x4 a = acc[mi][ni];
      #pragma unroll
      for (int r = 0; r < 4; ++r) C[(size_t)(mrow + r) * NV + vcol] = a[r] + bs;
    }
  }
}

// ---------------- launch ----------------
extern "C" void kernel_launch(void* const* d_in, const int* in_sizes, int n_in,
                              void* d_out, int out_size, void* d_ws, size_t ws_size,
                              hipStream_t stream) {
  (void)in_sizes; (void)n_in; (void)out_size;
  const int*   idx  = (const int*)d_in[0];
  const int*   src  = (const int*)d_in[1];
  const int*   dst  = (const int*)d_in[2];
  const float* Wemb = (const float*)d_in[3];
  const float* Gx   = (const float*)d_in[4];
  const float* Gy   = (const float*)d_in[5];
  const float* Gs   = (const float*)d_in[6];
  const float* Wout = (const float*)d_in[7];
  const float* bout = (const float*)d_in[8];
  float* out = (float*)d_out;
  float* sig_out = out + (size_t)NM * NV;   // logits first, then sigma

  char* p = (char*)d_ws;
  int*   bar     = (int*)p;                               // 1 KB arrive flags
  int*   rel     = (int*)(p + 1024);                      // 16 KB replicated release lines
  int*   cnt     = (int*)(p + 1024 + 16384);              // 16 KB
  float* sigma_s = (float*)(p + 1024 + 16384 + 16384);    // 512 KB (zero region ends here)
  size_t off = 1024 + 16384 + 16384 + (size_t)NE * 4;
  const size_t msz = off;
  int*   row_ptr = (int*)(p + off); off += 16640;          // 4097 ints, padded
  int*   cursor  = (int*)(p + off); off += 16384;
  int*   src_s   = (int*)(p + off); off += (size_t)NE * 4 + 16;  // +1 pad slot
  int*   orig_s  = (int*)(p + off); off += (size_t)NE * 4 + 16;
  float* Gx_s    = (float*)(p + off); off += (size_t)NE * 4 + 16;
  float* Gy_s    = (float*)(p + off); off += (size_t)NE * 4 + 16;
  float* Gs_s    = (float*)(p + off); off += (size_t)NE * 4 + 16;
  float* xybuf   = (float*)(p + off); off += (size_t)NN * NBAT * 8;  // interleaved x,y
  float* Abuf    = (float*)(p + off); off += (size_t)NN * NBAT * 4;
  float* Xbuf    = (float*)(p + off); off += (size_t)NT * NN * NBAT * 4;   // 16 MB
  unsigned short* Abf = (unsigned short*)(p + off); off += (size_t)NM * NK * 2; // 8 MB
  unsigned short* Wbf = (unsigned short*)(p + off); off += (size_t)NV * NK * 2; // 64 MB
  if (ws_size < off) return;   // ~92 MB required

  hipMemsetAsync(d_ws, 0, msz, stream);
  k_hist<<<NE / 256, 256, 0, stream>>>(dst, cnt);
  k_scan<<<1, 256, 0, stream>>>(cnt, row_ptr, cursor);
  k_build<<<NE / 256, 256, 0, stream>>>(src, dst, Gx, Gy, Gs, cursor,
                                        src_s, orig_s, Gx_s, Gy_s, Gs_s);
  k_gatherX<<<NT * 16, 256, 0, stream>>>(idx, Wemb, Xbuf, xybuf);
  k_convW<<<(NV * NK) / (256 * 8), 256, 0, stream>>>(Wout, Wbf);
  k_loop<<<COOP_BLOCKS + 1, COOP_THREADS, 0, stream>>>(row_ptr, src_s, Gx_s, Gy_s, Gs_s,
      sigma_s, Xbuf, xybuf, Abuf, Abf, bar, rel, orig_s, sig_out);
  k_gemm<<<dim3(NV / 128, NM / 128), 256, 0, stream>>>(Abf, Wbf, bout, out);
}

// Round 3
// 4205.056 us; speedup vs baseline: 1.3497x; 1.3497x over previous
//
#include <hip/hip_runtime.h>
#include <cstdint>
#include <cstddef>

#define NN   4096      // neurons
#define NE   131072    // edges
#define NBAT 8         // batch
#define NT   128       // timesteps
#define NV   8192      // vocab
#define NK   4096      // = NN (GEMM K)
#define NM   1024      // = NBAT*NT (GEMM M)
#define DECAYF 0.99f
#define COOP_BLOCKS 256
#define COOP_THREADS 1024   // 8 batch x 8 strips x 16 nodes
#define NBARRIERS (NT * 5)  // 5 grid barriers per timestep

typedef short bf16x8 __attribute__((ext_vector_type(8)));
typedef float f32x4 __attribute__((ext_vector_type(4)));
typedef unsigned short u16x8 __attribute__((ext_vector_type(8)));

// 6 register slots x 8 strips = 48 edges covered in registers per node;
// nodes with degree > 48 (P ~ 0.2%) take the memory tail path.
#define FOR_SLOTS(M) M(0) M(1) M(2) M(3) M(4) M(5)
#define SLOT_EDGES 48

__device__ __forceinline__ unsigned short f2bf(float f) {
  unsigned int u = __builtin_bit_cast(unsigned int, f);
  u = u + 0x7fffu + ((u >> 16) & 1u);   // round-to-nearest-even
  return (unsigned short)(u >> 16);
}

// Coherent (cross-XCD) access: bypasses L1/L2, served at the coherence point.
__device__ __forceinline__ float cload(const float* p) {
  return __hip_atomic_load(p, __ATOMIC_RELAXED, __HIP_MEMORY_SCOPE_AGENT);
}
__device__ __forceinline__ float2 cload2(const float* p) {
  unsigned long long v = __hip_atomic_load((const unsigned long long*)p,
                                           __ATOMIC_RELAXED, __HIP_MEMORY_SCOPE_AGENT);
  return __builtin_bit_cast(float2, v);
}
__device__ __forceinline__ void cstore(float* p, float v) {
  __hip_atomic_store(p, v, __ATOMIC_RELAXED, __HIP_MEMORY_SCOPE_AGENT);
}
__device__ __forceinline__ int cloadi(const int* p) {
  return __hip_atomic_load(p, __ATOMIC_RELAXED, __HIP_MEMORY_SCOPE_AGENT);
}
__device__ __forceinline__ void cstorei(int* p, int v) {
  __hip_atomic_store(p, v, __ATOMIC_RELAXED, __HIP_MEMORY_SCOPE_AGENT);
}

// ---------------- prologue: CSR build ----------------
__global__ void k_hist(const int* __restrict__ dst, int* __restrict__ cnt) {
  int e = blockIdx.x * 256 + threadIdx.x;
  if (e < NE) atomicAdd(&cnt[dst[e]], 1);
}

__global__ void k_scan(const int* __restrict__ cnt, int* __restrict__ row_ptr,
                       int* __restrict__ cursor) {
  __shared__ int lds[256];
  int tid = threadIdx.x;
  int base = tid * 16;
  int loc[16];
  int s = 0;
  #pragma unroll
  for (int i = 0; i < 16; ++i) { loc[i] = s; s += cnt[base + i]; }
  lds[tid] = s;
  __syncthreads();
  for (int off = 1; off < 256; off <<= 1) {
    int v = lds[tid];
    int a = (tid >= off) ? lds[tid - off] : 0;
    __syncthreads();
    lds[tid] = v + a;
    __syncthreads();
  }
  int myoff = (tid == 0) ? 0 : lds[tid - 1];
  #pragma unroll
  for (int i = 0; i < 16; ++i) {
    int rp = myoff + loc[i];
    row_ptr[base + i] = rp;
    cursor[base + i] = rp;
  }
  if (tid == 255) row_ptr[NN] = lds[255];
}

__global__ void k_build(const int* __restrict__ src, const int* __restrict__ dst,
                        const float* __restrict__ Gx, const float* __restrict__ Gy,
                        const float* __restrict__ Gs, int* __restrict__ cursor,
                        int* __restrict__ src_s, int* __restrict__ orig_s,
                        float* __restrict__ Gx_s, float* __restrict__ Gy_s,
                        float* __restrict__ Gs_s) {
  int e = blockIdx.x * 256 + threadIdx.x;
  if (e >= NE) return;
  if (e == 0) {   // zero pad slot at index NE: masks all pad contributions
    src_s[NE] = 0;
    Gx_s[NE] = 0.f; Gy_s[NE] = 0.f; Gs_s[NE] = 0.f;
  }
  int d = dst[e];
  int pos = atomicAdd(&cursor[d], 1);
  src_s[pos] = src[e];
  orig_s[pos] = e;
  Gx_s[pos] = Gx[e];
  Gy_s[pos] = Gy[e];
  Gs_s[pos] = Gs[e];
}

// Gather all embeddings into (T, N, B) layout; also init y-half of xybuf = X[:,0,:]
__global__ void k_gatherX(const int* __restrict__ idx, const float* __restrict__ Wemb,
                          float* __restrict__ Xbuf, float* __restrict__ xybuf) {
  __shared__ float tile[256 * 9];   // +1 pad stride to kill bank conflicts
  int t = blockIdx.x >> 4;
  int nc = (blockIdx.x & 15) << 8;
  int tid = threadIdx.x;
  #pragma unroll
  for (int bb = 0; bb < 8; ++bb) {
    int row = idx[bb * NT + t];     // idx is (B,T)
    tile[tid * 9 + bb] = Wemb[(size_t)row * NN + nc + tid];
  }
  __syncthreads();
  float* dp = Xbuf + (size_t)t * (NN * NBAT) + (size_t)nc * NBAT;
  #pragma unroll
  for (int kk = 0; kk < 8; ++kk) dp[tid * 8 + kk] = tile[tid * 9 + kk];
  if (t == 0) {
    float* yp = xybuf + (size_t)nc * NBAT * 2;
    #pragma unroll
    for (int kk = 0; kk < 8; ++kk) yp[((tid * 8 + kk) << 1) + 1] = tile[tid * 9 + kk];
  }
}

__global__ void k_convW(const float* __restrict__ W, unsigned short* __restrict__ Wbf) {
  size_t base = ((size_t)blockIdx.x * 256 + threadIdx.x) * 8;
  float4 a = *(const float4*)(W + base);
  float4 b = *(const float4*)(W + base + 4);
  u16x8 hv;
  hv[0] = f2bf(a.x); hv[1] = f2bf(a.y); hv[2] = f2bf(a.z); hv[3] = f2bf(a.w);
  hv[4] = f2bf(b.x); hv[5] = f2bf(b.y); hv[6] = f2bf(b.z); hv[7] = f2bf(b.w);
  *(u16x8*)(Wbf + base) = hv;
}

// ---------------- grid barrier ----------------
// bar[0..255]    : per-block monotone arrive generation (worker leader stores)
// rel[i*16]      : per-block REPLICATED release line (64B apart) -> each worker
//                  spins on its OWN line; master posts 256 lines / 4 wave stores.
__device__ __forceinline__ void gridbar(int* bar, int* rel, int& gen) {
  __syncthreads();   // vmcnt(0): all this block's coherent stores are at L3
  if (threadIdx.x == 0) {
    cstorei(&bar[blockIdx.x], gen + 1);
    while (cloadi(&rel[blockIdx.x << 4]) <= gen) __builtin_amdgcn_s_sleep(1);
  }
  ++gen;
  __syncthreads();
}

// ---------------- persistent recurrence kernel ----------------
// Worker blocks 0..255; block 256 = barrier master (wave 0 only).
// Worker mapping: g = b | h<<3 | n<<6 (b=batch lane, h=edge-strip, n=node).
// One wave = one node. First 48 edges of each node: gather address + sigma
// live in named scalar registers (sb0..sb5 / sg0..sg5 -- NO arrays, so no
// scratch). Inactive slots self-pad to the node's own entry (valid, distinct
// per wave, no hot line) and are masked by G*_s[NE] == 0.
// __launch_bounds__(1024, 8) caps VGPR at 64 -> 2 blocks/CU, all 257 resident.
__global__ __launch_bounds__(COOP_THREADS, 8) void k_loop(
    const int* __restrict__ row_ptr, const int* __restrict__ src_s,
    const float* __restrict__ Gx_s, const float* __restrict__ Gy_s,
    const float* __restrict__ Gs_s, float* __restrict__ sigma_s,
    const float* __restrict__ Xbuf, float* __restrict__ xybuf,
    float* __restrict__ Abuf, unsigned short* __restrict__ Abf,
    int* bar, int* rel,
    const int* __restrict__ orig_s, float* __restrict__ sig_out) {
  if (blockIdx.x == COOP_BLOCKS) {
    // ---- barrier master: wave 0 sweeps 256 arrive flags, posts 256 lines ----
    if (threadIdx.x < 64) {
      const int lane = threadIdx.x;
      for (int g = 1; g <= NBARRIERS; ++g) {
        for (;;) {
          int v0 = cloadi(&bar[lane]);
          int v1 = cloadi(&bar[lane + 64]);
          int v2 = cloadi(&bar[lane + 128]);
          int v3 = cloadi(&bar[lane + 192]);
          int m = min(min(v0, v1), min(v2, v3));
          #pragma unroll
          for (int d = 1; d < 64; d <<= 1) m = min(m, __shfl_xor(m, d));
          if (m >= g) break;
        }
        #pragma unroll
        for (int k = 0; k < 4; ++k) cstorei(&rel[(lane + k * 64) << 4], g);
      }
    }
    return;
  }

  const int tid = threadIdx.x;
  const int g = blockIdx.x * COOP_THREADS + tid;
  const int b = g & 7;
  const int h = (g >> 3) & 7;
  const int n = g >> 6;
  const int rs = row_ptr[n];
  const int re = row_ptr[n + 1];
  const int rh = rs + h;
  const int nb8 = (n << 3) | b;
  const int nb16 = nb8 << 1;
  int gen = 0;

  // named scalar slot state (slot i covers edge jc = rs + h + 8*i)
  int   sb0, sb1, sb2, sb3, sb4, sb5;
  float sg0, sg1, sg2, sg3, sg4, sg5;
#define M(i) { int jc = rh + 8 * (i); \
    sb##i = (jc < re) ? ((src_s[jc] << 3) | b) : nb8; sg##i = 0.f; }
  FOR_SLOTS(M)
#undef M
  const bool tail = (re - rs) > SLOT_EDGES;   // memory fallback, wave-uniform

  for (int t = 0; t < NT; ++t) {
    const float* xp = Xbuf + (size_t)t * (NN * NBAT);
    #pragma unroll
    for (int layer = 0; layer < 2; ++layer) {
      // ---- S12: A[b,n] = sum x[b,src]*sigma ; hebbian ; sigma update ----
      {
        float xn = (layer == 0) ? xp[nb8] : cload(&xybuf[nb16]);
        // issue all gathers first (MLP), then the dependent chain
#define M(i) float xv##i, yv##i; \
        if (layer == 0) { xv##i = xp[sb##i]; yv##i = cload(&xybuf[(sb##i << 1) + 1]); } \
        else { float2 p2 = cload2(&xybuf[sb##i << 1]); xv##i = p2.x; yv##i = p2.y; }
        FOR_SLOTS(M)
#undef M
        float acc = 0.f;
#define M(i) { acc = fmaf(xv##i, sg##i, acc); /* OLD sigma (matches ref) */ \
        float pv = yv##i * xn;                /* y_t[b,src]*x_t[b,dst] */ \
        pv += __shfl_xor(pv, 1); \
        pv += __shfl_xor(pv, 2); \
        pv += __shfl_xor(pv, 4);              /* sum over 8 batch lanes */ \
        int jc = rh + 8 * (i); int j = (jc < re) ? jc : NE; \
        sg##i = (sg##i + pv * 0.125f * Gs_s[j]) * DECAYF; }
        FOR_SLOTS(M)
#undef M
        if (tail) {
          for (int j = rs + SLOT_EDGES + h; j < re; j += 8) {
            int sb2 = ((src_s[j] << 3) | b) << 1;
            float xvr = (layer == 0) ? xp[sb2 >> 1] : cload(&xybuf[sb2]);
            float yvr = cload(&xybuf[sb2 + 1]);
            float sgr = sigma_s[j];
            acc = fmaf(xvr, sgr, acc);
            float pvr = yvr * xn;
            pvr += __shfl_xor(pvr, 1);
            pvr += __shfl_xor(pvr, 2);
            pvr += __shfl_xor(pvr, 4);
            if (b == 0) sigma_s[j] = (sgr + pvr * 0.125f * Gs_s[j]) * DECAYF;
          }
        }
        acc += __shfl_xor(acc, 8);
        acc += __shfl_xor(acc, 16);
        acc += __shfl_xor(acc, 32);           // combine 8 edge-strips
        if (h == 0) cstore(&Abuf[nb8], acc);
      }
      gridbar(bar, rel, gen);
      // ---- S3: y[b,n] = sum relu(A[b,src])*Gy ----
      {
        float acc = 0.f;
#define M(i) float av##i = cload(&Abuf[sb##i]);
        FOR_SLOTS(M)
#undef M
#define M(i) { int jc = rh + 8 * (i); int j = (jc < re) ? jc : NE; \
        acc = fmaf(fmaxf(av##i, 0.f), Gy_s[j], acc); }
        FOR_SLOTS(M)
#undef M
        if (tail)
          for (int j = rs + SLOT_EDGES + h; j < re; j += 8)
            acc = fmaf(fmaxf(cload(&Abuf[(src_s[j] << 3) | b]), 0.f), Gy_s[j], acc);
        acc += __shfl_xor(acc, 8);
        acc += __shfl_xor(acc, 16);
        acc += __shfl_xor(acc, 32);
        if (h == 0) cstore(&xybuf[nb16 + 1], acc);
      }
      gridbar(bar, rel, gen);
      // ---- S4: x[b,n] = relu(sum y[b,src]*Gx) ----
      {
        float acc = 0.f;
#define M(i) float wv##i = cload(&xybuf[(sb##i << 1) + 1]);
        FOR_SLOTS(M)
#undef M
#define M(i) { int jc = rh + 8 * (i); int j = (jc < re) ? jc : NE; \
        acc = fmaf(wv##i, Gx_s[j], acc); }
        FOR_SLOTS(M)
#undef M
        if (tail)
          for (int j = rs + SLOT_EDGES + h; j < re; j += 8)
            acc = fmaf(cload(&xybuf[(((src_s[j] << 3) | b) << 1) + 1]), Gx_s[j], acc);
        acc += __shfl_xor(acc, 8);
        acc += __shfl_xor(acc, 16);
        acc += __shfl_xor(acc, 32);
        if (layer == 0) {
          if (h == 0) cstore(&xybuf[nb16], fmaxf(acc, 0.f));
          gridbar(bar, rel, gen);
        } else if (h == 0) {
          // xs output straight into GEMM A-matrix (bf16), row m = b*T+t
          Abf[(size_t)((b << 7) | t) * NK + n] = f2bf(fmaxf(acc, 0.f));
        }
      }
      // no barrier after layer-2 S4: next step's x comes from Xbuf, and y/sigma
      // are produced before the next barrier; Abf is consumed post-kernel.
    }
  }
  // epilogue: sigma (registers + rare memory tail) back to original edge order
  if (b == 0) {
#define M(i) { int jc = rh + 8 * (i); if (jc < re) sig_out[orig_s[jc]] = sg##i; }
    FOR_SLOTS(M)
#undef M
    if (tail)
      for (int j = rs + SLOT_EDGES + h; j < re; j += 8) sig_out[orig_s[j]] = sigma_s[j];
  }
}

// ---------------- bf16 MFMA GEMM: C[m,v] = sum_k A[m,k]*Bw[v,k] + bias[v] ----------------
__global__ __launch_bounds__(256) void k_gemm(const unsigned short* __restrict__ A,
                                              const unsigned short* __restrict__ Bw,
                                              const float* __restrict__ bias,
                                              float* __restrict__ C) {
  __shared__ __align__(16) unsigned short As[128 * 32];
  __shared__ __align__(16) unsigned short Bs[128 * 32];
  const int m0 = blockIdx.y * 128;
  const int v0 = blockIdx.x * 128;
  const int wave = threadIdx.x >> 6;
  const int lane = threadIdx.x & 63;
  const int wm = wave >> 1;
  const int wv = wave & 1;
  f32x4 acc[4][4] = {};

  const int srow = lane >> 2;
  const int skc = (lane & 3) * 8;

  for (int k0 = 0; k0 < NK; k0 += 32) {
    #pragma unroll
    for (int c = 0; c < 2; ++c) {
      int chunk = wave * 2 + c;
      int row = chunk * 16 + srow;
      __builtin_amdgcn_global_load_lds(
          (const __attribute__((address_space(1))) void*)(A + (size_t)(m0 + row) * NK + k0 + skc),
          (__attribute__((address_space(3))) void*)(As + chunk * 512), 16, 0, 0);
      __builtin_amdgcn_global_load_lds(
          (const __attribute__((address_space(1))) void*)(Bw + (size_t)(v0 + row) * NK + k0 + skc),
          (__attribute__((address_space(3))) void*)(Bs + chunk * 512), 16, 0, 0);
    }
    __syncthreads();
    bf16x8 af[4], bq[4];
    #pragma unroll
    for (int mi = 0; mi < 4; ++mi)
      af[mi] = *(const bf16x8*)(As + ((wm * 64 + mi * 16 + (lane & 15)) * 32 + (lane >> 4) * 8));
    #pragma unroll
    for (int ni = 0; ni < 4; ++ni)
      bq[ni] = *(const bf16x8*)(Bs + ((wv * 64 + ni * 16 + (lane & 15)) * 32 + (lane >> 4) * 8));
    #pragma unroll
    for (int mi = 0; mi < 4; ++mi)
      #pragma unroll
      for (int ni = 0; ni < 4; ++ni)
        acc[mi][ni] = __builtin_amdgcn_mfma_f32_16x16x32_bf16(af[mi], bq[ni], acc[mi][ni], 0, 0, 0);
    __syncthreads();
  }

  #pragma unroll
  for (int mi = 0; mi < 4; ++mi) {
    int mrow = m0 + wm * 64 + mi * 16 + ((lane >> 4) << 2);
    #pragma unroll
    for (int ni = 0; ni < 4; ++ni) {
      int vcol = v0 + wv * 64 + ni * 16 + (lane & 15);
      float bs = bias[vcol];
      f32x4 a = acc[mi][ni];
      #pragma unroll
      for (int r = 0; r < 4; ++r) C[(size_t)(mrow + r) * NV + vcol] = a[r] + bs;
    }
  }
}

// ---------------- launch ----------------
extern "C" void kernel_launch(void* const* d_in, const int* in_sizes, int n_in,
                              void* d_out, int out_size, void* d_ws, size_t ws_size,
                              hipStream_t stream) {
  (void)in_sizes; (void)n_in; (void)out_size;
  const int*   idx  = (const int*)d_in[0];
  const int*   src  = (const int*)d_in[1];
  const int*   dst  = (const int*)d_in[2];
  const float* Wemb = (const float*)d_in[3];
  const float* Gx   = (const float*)d_in[4];
  const float* Gy   = (const float*)d_in[5];
  const float* Gs   = (const float*)d_in[6];
  const float* Wout = (const float*)d_in[7];
  const float* bout = (const float*)d_in[8];
  float* out = (float*)d_out;
  float* sig_out = out + (size_t)NM * NV;   // logits first, then sigma

  char* p = (char*)d_ws;
  int*   bar     = (int*)p;                               // 1 KB arrive flags
  int*   rel     = (int*)(p + 1024);                      // 16 KB replicated release lines
  int*   cnt     = (int*)(p + 1024 + 16384);              // 16 KB
  float* sigma_s = (float*)(p + 1024 + 16384 + 16384);    // 512 KB (zero region ends here)
  size_t off = 1024 + 16384 + 16384 + (size_t)NE * 4;
  const size_t msz = off;
  int*   row_ptr = (int*)(p + off); off += 16640;          // 4097 ints, padded
  int*   cursor  = (int*)(p + off); off += 16384;
  int*   src_s   = (int*)(p + off); off += (size_t)NE * 4 + 16;  // +1 pad slot
  int*   orig_s  = (int*)(p + off); off += (size_t)NE * 4 + 16;
  float* Gx_s    = (float*)(p + off); off += (size_t)NE * 4 + 16;
  float* Gy_s    = (float*)(p + off); off += (size_t)NE * 4 + 16;
  float* Gs_s    = (float*)(p + off); off += (size_t)NE * 4 + 16;
  float* xybuf   = (float*)(p + off); off += (size_t)NN * NBAT * 8;  // interleaved x,y
  float* Abuf    = (float*)(p + off); off += (size_t)NN * NBAT * 4;
  float* Xbuf    = (float*)(p + off); off += (size_t)NT * NN * NBAT * 4;   // 16 MB
  unsigned short* Abf = (unsigned short*)(p + off); off += (size_t)NM * NK * 2; // 8 MB
  unsigned short* Wbf = (unsigned short*)(p + off); off += (size_t)NV * NK * 2; // 64 MB
  if (ws_size < off) return;   // ~92 MB required

  hipMemsetAsync(d_ws, 0, msz, stream);
  k_hist<<<NE / 256, 256, 0, stream>>>(dst, cnt);
  k_scan<<<1, 256, 0, stream>>>(cnt, row_ptr, cursor);
  k_build<<<NE / 256, 256, 0, stream>>>(src, dst, Gx, Gy, Gs, cursor,
                                        src_s, orig_s, Gx_s, Gy_s, Gs_s);
  k_gatherX<<<NT * 16, 256, 0, stream>>>(idx, Wemb, Xbuf, xybuf);
  k_convW<<<(NV * NK) / (256 * 8), 256, 0, stream>>>(Wout, Wbf);
  k_loop<<<COOP_BLOCKS + 1, COOP_THREADS, 0, stream>>>(row_ptr, src_s, Gx_s, Gy_s, Gs_s,
      sigma_s, Xbuf, xybuf, Abuf, Abf, bar, rel, orig_s, sig_out);
  k_gemm<<<dim3(NV / 128, NM / 128), 256, 0, stream>>>(Abf, Wbf, bout, out);
}

// Round 6
// 3299.060 us; speedup vs baseline: 1.7204x; 1.2746x over previous
//
#include <hip/hip_runtime.h>
#include <cstdint>
#include <cstddef>

#define NN   4096      // neurons
#define NE   131072    // edges
#define NBAT 8         // batch
#define NT   128       // timesteps
#define NV   8192      // vocab
#define NK   4096      // = NN (GEMM K)
#define NM   1024      // = NBAT*NT (GEMM M)
#define DECAYF 0.99f
#define COOP_BLOCKS 256
#define COOP_THREADS 1024   // 8 batch x 8 strips x 16 nodes
#define NBARRIERS (NT * 5)  // 5 grid barriers per timestep

typedef short bf16x8 __attribute__((ext_vector_type(8)));
typedef float f32x4 __attribute__((ext_vector_type(4)));
typedef unsigned short u16x8 __attribute__((ext_vector_type(8)));

__device__ __forceinline__ unsigned short f2bf(float f) {
  unsigned int u = __builtin_bit_cast(unsigned int, f);
  u = u + 0x7fffu + ((u >> 16) & 1u);   // round-to-nearest-even
  return (unsigned short)(u >> 16);
}

// Coherent (cross-XCD) access: sc0 sc1, bypasses L1/L2, served at the
// memory-side coherence point. No fences needed anywhere.
__device__ __forceinline__ float cload(const float* p) {
  return __hip_atomic_load(p, __ATOMIC_RELAXED, __HIP_MEMORY_SCOPE_AGENT);
}
__device__ __forceinline__ void cstore(float* p, float v) {
  __hip_atomic_store(p, v, __ATOMIC_RELAXED, __HIP_MEMORY_SCOPE_AGENT);
}
__device__ __forceinline__ int cloadi(const int* p) {
  return __hip_atomic_load(p, __ATOMIC_RELAXED, __HIP_MEMORY_SCOPE_AGENT);
}
__device__ __forceinline__ void cstorei(int* p, int v) {
  __hip_atomic_store(p, v, __ATOMIC_RELAXED, __HIP_MEMORY_SCOPE_AGENT);
}

// ---------------- prologue: CSR build ----------------
__global__ void k_hist(const int* __restrict__ dst, int* __restrict__ cnt) {
  int e = blockIdx.x * 256 + threadIdx.x;
  if (e < NE) atomicAdd(&cnt[dst[e]], 1);
}

__global__ void k_scan(const int* __restrict__ cnt, int* __restrict__ row_ptr,
                       int* __restrict__ cursor) {
  __shared__ int lds[256];
  int tid = threadIdx.x;
  int base = tid * 16;
  int loc[16];
  int s = 0;
  #pragma unroll
  for (int i = 0; i < 16; ++i) { loc[i] = s; s += cnt[base + i]; }
  lds[tid] = s;
  __syncthreads();
  for (int off = 1; off < 256; off <<= 1) {
    int v = lds[tid];
    int a = (tid >= off) ? lds[tid - off] : 0;
    __syncthreads();
    lds[tid] = v + a;
    __syncthreads();
  }
  int myoff = (tid == 0) ? 0 : lds[tid - 1];
  #pragma unroll
  for (int i = 0; i < 16; ++i) {
    int rp = myoff + loc[i];
    row_ptr[base + i] = rp;
    cursor[base + i] = rp;
  }
  if (tid == 255) row_ptr[NN] = lds[255];
}

__global__ void k_build(const int* __restrict__ src, const int* __restrict__ dst,
                        const float* __restrict__ Gx, const float* __restrict__ Gy,
                        const float* __restrict__ Gs, int* __restrict__ cursor,
                        int* __restrict__ src_s, int* __restrict__ orig_s,
                        float* __restrict__ Gx_s, float* __restrict__ Gy_s,
                        float* __restrict__ Gs_s) {
  int e = blockIdx.x * 256 + threadIdx.x;
  if (e >= NE) return;
  int d = dst[e];
  int pos = atomicAdd(&cursor[d], 1);
  src_s[pos] = src[e];
  orig_s[pos] = e;
  Gx_s[pos] = Gx[e];
  Gy_s[pos] = Gy[e];
  Gs_s[pos] = Gs[e];
}

// Gather all embeddings into (T, N, B) layout; also init y0 = X[:,0,:]
__global__ void k_gatherX(const int* __restrict__ idx, const float* __restrict__ Wemb,
                          float* __restrict__ Xbuf, float* __restrict__ ybuf) {
  __shared__ float tile[256 * 9];   // +1 pad stride to kill bank conflicts
  int t = blockIdx.x >> 4;
  int nc = (blockIdx.x & 15) << 8;
  int tid = threadIdx.x;
  #pragma unroll
  for (int bb = 0; bb < 8; ++bb) {
    int row = idx[bb * NT + t];     // idx is (B,T)
    tile[tid * 9 + bb] = Wemb[(size_t)row * NN + nc + tid];
  }
  __syncthreads();
  float* dp = Xbuf + (size_t)t * (NN * NBAT) + (size_t)nc * NBAT;
  #pragma unroll
  for (int kk = 0; kk < 8; ++kk) dp[tid * 8 + kk] = tile[tid * 9 + kk];
  if (t == 0) {
    float* yp = ybuf + (size_t)nc * NBAT;
    #pragma unroll
    for (int kk = 0; kk < 8; ++kk) yp[tid * 8 + kk] = tile[tid * 9 + kk];
  }
}

__global__ void k_convW(const float* __restrict__ W, unsigned short* __restrict__ Wbf) {
  size_t base = ((size_t)blockIdx.x * 256 + threadIdx.x) * 8;
  float4 a = *(const float4*)(W + base);
  float4 b = *(const float4*)(W + base + 4);
  u16x8 hv;
  hv[0] = f2bf(a.x); hv[1] = f2bf(a.y); hv[2] = f2bf(a.z); hv[3] = f2bf(a.w);
  hv[4] = f2bf(b.x); hv[5] = f2bf(b.y); hv[6] = f2bf(b.z); hv[7] = f2bf(b.w);
  *(u16x8*)(Wbf + base) = hv;
}

// ---------------- grid barrier: store-arrive + master poller ----------------
// bar[0..255]   : per-block monotone arrive generation (worker leader stores)
// rel[i*16]     : per-block REPLICATED release line (64B apart). Only change
//                 vs the 3.09ms baseline: workers spin on their own line
//                 instead of all 256 leaders polling one shared word.
//                 (This exact barrier ran 640 generations in R2 and R3.)
__device__ __forceinline__ void gridbar(int* bar, int* rel, int& gen) {
  __syncthreads();
  if (threadIdx.x == 0) {
    cstorei(&bar[blockIdx.x], gen + 1);
    while (cloadi(&rel[blockIdx.x << 4]) <= gen) __builtin_amdgcn_s_sleep(1);
  }
  ++gen;
  __syncthreads();
}

// ---------------- persistent recurrence kernel ----------------
// Worker blocks 0..255; block 256 = barrier master (wave 0 only).
// Worker mapping: g = b | h<<3 | n<<6 (b=batch lane, h=edge-strip, n=node).
// One wave = one node (8 batch x 8 strips). 16 nodes / block.
__global__ __launch_bounds__(COOP_THREADS, 8) void k_loop(
    const int* __restrict__ row_ptr, const int* __restrict__ src_s,
    const float* __restrict__ Gx_s, const float* __restrict__ Gy_s,
    const float* __restrict__ Gs_s, float* __restrict__ sigma_s,
    const float* __restrict__ Xbuf, float* __restrict__ ybuf,
    float* __restrict__ xbuf, float* __restrict__ Abuf,
    unsigned short* __restrict__ Abf, int* bar, int* rel,
    const int* __restrict__ orig_s, float* __restrict__ sig_out) {
  if (blockIdx.x == COOP_BLOCKS) {
    // ---- barrier master: wave 0 polls 256 arrive flags (R3's proven
    // indexing), posts release to 256 replicated lines (4 wave stores). ----
    if (threadIdx.x < 64) {
      const int lane = threadIdx.x;
      for (int g = 1; g <= NBARRIERS; ++g) {
        for (;;) {
          int v0 = cloadi(&bar[lane]);
          int v1 = cloadi(&bar[lane + 64]);
          int v2 = cloadi(&bar[lane + 128]);
          int v3 = cloadi(&bar[lane + 192]);
          int m = min(min(v0, v1), min(v2, v3));
          #pragma unroll
          for (int d = 1; d < 64; d <<= 1) m = min(m, __shfl_xor(m, d));
          if (m >= g) break;
        }
        #pragma unroll
        for (int k = 0; k < 4; ++k) cstorei(&rel[(lane + k * 64) << 4], g);
      }
    }
    return;
  }

  const int tid = threadIdx.x;
  const int g = blockIdx.x * COOP_THREADS + tid;
  const int b = g & 7;
  const int h = (g >> 3) & 7;
  const int n = g >> 6;
  const int rs = row_ptr[n];
  const int re = row_ptr[n + 1];
  const int nb8 = (n << 3) | b;
  int gen = 0;

  for (int t = 0; t < NT; ++t) {
    const float* xp = Xbuf + (size_t)t * (NN * NBAT);
    #pragma unroll
    for (int layer = 0; layer < 2; ++layer) {
      // ---- S12: A[b,n] = sum x[b,src]*sigma ; hebbian ; sigma update ----
      {
        float xn = (layer == 0) ? xp[nb8] : cload(&xbuf[nb8]);
        float acc = 0.f;
        for (int j = rs + h; j < re; j += 32) {
          int jj[4], sv[4];
          float sg[4], gs[4], xv[4], yv[4];
          bool act[4];
          #pragma unroll
          for (int u = 0; u < 4; ++u) {
            int jc = j + (u << 3);
            act[u] = jc < re;
            jj[u] = act[u] ? jc : j;     // clamped-safe index
          }
          #pragma unroll
          for (int u = 0; u < 4; ++u) sv[u] = src_s[jj[u]];
          #pragma unroll
          for (int u = 0; u < 4; ++u) {
            float sgu = sigma_s[jj[u]];
            float gsu = Gs_s[jj[u]];
            sg[u] = act[u] ? sgu : 0.f;
            gs[u] = act[u] ? gsu : 0.f;
          }
          #pragma unroll
          for (int u = 0; u < 4; ++u) {
            int sb = (sv[u] << 3) | b;
            xv[u] = (layer == 0) ? xp[sb] : cload(&xbuf[sb]);
            yv[u] = cload(&ybuf[sb]);
          }
          #pragma unroll
          for (int u = 0; u < 4; ++u) {
            acc = fmaf(xv[u], sg[u], acc);      // OLD sigma (matches ref)
            float pv = yv[u] * xn;              // y_t[b,src]*x_t[b,dst]
            pv += __shfl_xor(pv, 1);
            pv += __shfl_xor(pv, 2);
            pv += __shfl_xor(pv, 4);            // sum over 8 batch lanes
            if (b == 0 && act[u])
              sigma_s[jj[u]] = (sg[u] + pv * 0.125f * gs[u]) * DECAYF;
          }
        }
        acc += __shfl_xor(acc, 8);
        acc += __shfl_xor(acc, 16);
        acc += __shfl_xor(acc, 32);             // combine 8 edge-strips
        if (h == 0) cstore(&Abuf[nb8], acc);
      }
      gridbar(bar, rel, gen);
      // ---- S3: y[b,n] = sum relu(A[b,src])*Gy ----
      {
        float acc = 0.f;
        for (int j = rs + h; j < re; j += 32) {
          int jj[4], sv[4];
          float gy[4], av[4];
          bool act[4];
          #pragma unroll
          for (int u = 0; u < 4; ++u) {
            int jc = j + (u << 3);
            act[u] = jc < re;
            jj[u] = act[u] ? jc : j;
          }
          #pragma unroll
          for (int u = 0; u < 4; ++u) sv[u] = src_s[jj[u]];
          #pragma unroll
          for (int u = 0; u < 4; ++u) {
            float gyu = Gy_s[jj[u]];
            gy[u] = act[u] ? gyu : 0.f;
          }
          #pragma unroll
          for (int u = 0; u < 4; ++u) av[u] = cload(&Abuf[(sv[u] << 3) | b]);
          #pragma unroll
          for (int u = 0; u < 4; ++u) acc = fmaf(fmaxf(av[u], 0.f), gy[u], acc);
        }
        acc += __shfl_xor(acc, 8);
        acc += __shfl_xor(acc, 16);
        acc += __shfl_xor(acc, 32);
        if (h == 0) cstore(&ybuf[nb8], acc);
      }
      gridbar(bar, rel, gen);
      // ---- S4: x[b,n] = relu(sum y[b,src]*Gx) ----
      {
        float acc = 0.f;
        for (int j = rs + h; j < re; j += 32) {
          int jj[4], sv[4];
          float gx[4], yv[4];
          bool act[4];
          #pragma unroll
          for (int u = 0; u < 4; ++u) {
            int jc = j + (u << 3);
            act[u] = jc < re;
            jj[u] = act[u] ? jc : j;
          }
          #pragma unroll
          for (int u = 0; u < 4; ++u) sv[u] = src_s[jj[u]];
          #pragma unroll
          for (int u = 0; u < 4; ++u) {
            float gxu = Gx_s[jj[u]];
            gx[u] = act[u] ? gxu : 0.f;
          }
          #pragma unroll
          for (int u = 0; u < 4; ++u) yv[u] = cload(&ybuf[(sv[u] << 3) | b]);
          #pragma unroll
          for (int u = 0; u < 4; ++u) acc = fmaf(yv[u], gx[u], acc);
        }
        acc += __shfl_xor(acc, 8);
        acc += __shfl_xor(acc, 16);
        acc += __shfl_xor(acc, 32);
        if (layer == 0) {
          if (h == 0) cstore(&xbuf[nb8], fmaxf(acc, 0.f));
        } else if (h == 0) {
          // xs output straight into GEMM A-matrix (bf16), row m = b*T+t
          Abf[(size_t)((b << 7) | t) * NK + n] = f2bf(fmaxf(acc, 0.f));
        }
      }
      if (layer == 0) {
        gridbar(bar, rel, gen);
        xp = xbuf;
      }
      // no barrier after layer-2 S4: next step's x comes from Xbuf, and y/sigma
      // are produced before the next barrier; Abf is consumed post-kernel.
    }
  }
  // epilogue: sigma back to original edge order (block-local rows only)
  __syncthreads();
  int jlo = row_ptr[blockIdx.x * 16];
  int jhi = row_ptr[blockIdx.x * 16 + 16];
  for (int j = jlo + tid; j < jhi; j += COOP_THREADS) sig_out[orig_s[j]] = sigma_s[j];
}

// ---------------- bf16 MFMA GEMM: C[m,v] = sum_k A[m,k]*Bw[v,k] + bias[v] ----------------
__global__ __launch_bounds__(256) void k_gemm(const unsigned short* __restrict__ A,
                                              const unsigned short* __restrict__ Bw,
                                              const float* __restrict__ bias,
                                              float* __restrict__ C) {
  __shared__ __align__(16) unsigned short As[128 * 32];
  __shared__ __align__(16) unsigned short Bs[128 * 32];
  const int m0 = blockIdx.y * 128;
  const int v0 = blockIdx.x * 128;
  const int wave = threadIdx.x >> 6;
  const int lane = threadIdx.x & 63;
  const int wm = wave >> 1;
  const int wv = wave & 1;
  f32x4 acc[4][4] = {};

  const int srow = lane >> 2;
  const int skc = (lane & 3) * 8;

  for (int k0 = 0; k0 < NK; k0 += 32) {
    #pragma unroll
    for (int c = 0; c < 2; ++c) {
      int chunk = wave * 2 + c;
      int row = chunk * 16 + srow;
      __builtin_amdgcn_global_load_lds(
          (const __attribute__((address_space(1))) void*)(A + (size_t)(m0 + row) * NK + k0 + skc),
          (__attribute__((address_space(3))) void*)(As + chunk * 512), 16, 0, 0);
      __builtin_amdgcn_global_load_lds(
          (const __attribute__((address_space(1))) void*)(Bw + (size_t)(v0 + row) * NK + k0 + skc),
          (__attribute__((address_space(3))) void*)(Bs + chunk * 512), 16, 0, 0);
    }
    __syncthreads();
    bf16x8 af[4], bq[4];
    #pragma unroll
    for (int mi = 0; mi < 4; ++mi)
      af[mi] = *(const bf16x8*)(As + ((wm * 64 + mi * 16 + (lane & 15)) * 32 + (lane >> 4) * 8));
    #pragma unroll
    for (int ni = 0; ni < 4; ++ni)
      bq[ni] = *(const bf16x8*)(Bs + ((wv * 64 + ni * 16 + (lane & 15)) * 32 + (lane >> 4) * 8));
    #pragma unroll
    for (int mi = 0; mi < 4; ++mi)
      #pragma unroll
      for (int ni = 0; ni < 4; ++ni)
        acc[mi][ni] = __builtin_amdgcn_mfma_f32_16x16x32_bf16(af[mi], bq[ni], acc[mi][ni], 0, 0, 0);
    __syncthreads();
  }

  #pragma unroll
  for (int mi = 0; mi < 4; ++mi) {
    int mrow = m0 + wm * 64 + mi * 16 + ((lane >> 4) << 2);
    #pragma unroll
    for (int ni = 0; ni < 4; ++ni) {
      int vcol = v0 + wv * 64 + ni * 16 + (lane & 15);
      float bs = bias[vcol];
      f32x4 a = acc[mi][ni];
      #pragma unroll
      for (int r = 0; r < 4; ++r) C[(size_t)(mrow + r) * NV + vcol] = a[r] + bs;
    }
  }
}

// ---------------- launch ----------------
extern "C" void kernel_launch(void* const* d_in, const int* in_sizes, int n_in,
                              void* d_out, int out_size, void* d_ws, size_t ws_size,
                              hipStream_t stream) {
  (void)in_sizes; (void)n_in; (void)out_size;
  const int*   idx  = (const int*)d_in[0];
  const int*   src  = (const int*)d_in[1];
  const int*   dst  = (const int*)d_in[2];
  const float* Wemb = (const float*)d_in[3];
  const float* Gx   = (const float*)d_in[4];
  const float* Gy   = (const float*)d_in[5];
  const float* Gs   = (const float*)d_in[6];
  const float* Wout = (const float*)d_in[7];
  const float* bout = (const float*)d_in[8];
  float* out = (float*)d_out;
  float* sig_out = out + (size_t)NM * NV;   // logits first, then sigma

  char* p = (char*)d_ws;
  int*   bar     = (int*)p;                               // 2 KB arrive flags
  int*   rel     = (int*)(p + 2048);                      // 16 KB replicated release lines
  int*   cnt     = (int*)(p + 2048 + 16384);              // 16 KB
  float* sigma_s = (float*)(p + 2048 + 16384 + 16384);    // 512 KB (zero region ends here)
  size_t off = 2048 + 16384 + 16384 + (size_t)NE * 4;
  const size_t msz = off;
  int*   row_ptr = (int*)(p + off); off += 16640;          // 4097 ints, padded
  int*   cursor  = (int*)(p + off); off += 16384;
  int*   src_s   = (int*)(p + off); off += (size_t)NE * 4;
  int*   orig_s  = (int*)(p + off); off += (size_t)NE * 4;
  float* Gx_s    = (float*)(p + off); off += (size_t)NE * 4;
  float* Gy_s    = (float*)(p + off); off += (size_t)NE * 4;
  float* Gs_s    = (float*)(p + off); off += (size_t)NE * 4;
  float* ybuf    = (float*)(p + off); off += (size_t)NN * NBAT * 4;
  float* xbuf    = (float*)(p + off); off += (size_t)NN * NBAT * 4;
  float* Abuf    = (float*)(p + off); off += (size_t)NN * NBAT * 4;
  float* Xbuf    = (float*)(p + off); off += (size_t)NT * NN * NBAT * 4;   // 16 MB
  unsigned short* Abf = (unsigned short*)(p + off); off += (size_t)NM * NK * 2; // 8 MB
  unsigned short* Wbf = (unsigned short*)(p + off); off += (size_t)NV * NK * 2; // 64 MB
  if (ws_size < off) return;   // ~92 MB required

  hipMemsetAsync(d_ws, 0, msz, stream);
  k_hist<<<NE / 256, 256, 0, stream>>>(dst, cnt);
  k_scan<<<1, 256, 0, stream>>>(cnt, row_ptr, cursor);
  k_build<<<NE / 256, 256, 0, stream>>>(src, dst, Gx, Gy, Gs, cursor,
                                        src_s, orig_s, Gx_s, Gy_s, Gs_s);
  k_gatherX<<<NT * 16, 256, 0, stream>>>(idx, Wemb, Xbuf, ybuf);
  k_convW<<<(NV * NK) / (256 * 8), 256, 0, stream>>>(Wout, Wbf);
  k_loop<<<COOP_BLOCKS + 1, COOP_THREADS, 0, stream>>>(row_ptr, src_s, Gx_s, Gy_s, Gs_s,
      sigma_s, Xbuf, ybuf, xbuf, Abuf, Abf, bar, rel, orig_s, sig_out);
  k_gemm<<<dim3(NV / 128, NM / 128), 256, 0, stream>>>(Abf, Wbf, bout, out);
}